// Round 12
// baseline (448.155 us; speedup 1.0000x reference)
//
#include <hip/hip_runtime.h>
#include <math.h>

#define NF 15552      // B*T
#define NJ 17
#define NC 128
#define JC 2176       // NJ*NC
#define TT 243        // frames per batch

constexpr int cA[15] = {0,1,2,0,4,5,0,7,8,0,10,11,0,13,14};
constexpr int cB[15] = {1,2,3,4,5,6,7,8,9,10,11,12,13,14,15};
constexpr int aJ[4] = {11,14,5,8};
constexpr int aP[4] = {10,13,4,7};
constexpr int aCc[4] = {12,15,6,9};

__device__ const int d_cA16[16] = {0,1,2,0,4,5,0,7,8,0,10,11,0,13,14,0};
__device__ const int d_cB16[16] = {1,2,3,4,5,6,7,8,9,10,11,12,13,14,15,0};

typedef __bf16 bf16x8 __attribute__((ext_vector_type(8)));
typedef float f32x4 __attribute__((ext_vector_type(4)));
typedef unsigned short u16x8 __attribute__((ext_vector_type(8)));

// ws layout (bytes):
//   [0)       mean_acc  64*JC f32   = 557056
//   [557056)  wb frags  65536
//   [622592)  wa frags  16384
//   [638976)  feat bf16 NF*JC*2     = 67682304   (only if ws_size permits)
#define WSO_WB  557056
#define WSO_WA  622592
#define WSO_F16 638976
#define WS_NEED (638976ull + (unsigned long long)NF*JC*2)

__device__ __forceinline__ float gelu_exact(float x){
  return 0.5f * x * (1.0f + erff(x * 0.7071067811865476f));
}
__device__ __forceinline__ float gelu_fast(float x){
  const float s2 = x * x;
  const float q  = fmaf(s2, -0.1029437f, -2.3021183f);
  const float e  = __builtin_amdgcn_exp2f(q * x);
  return x * __builtin_amdgcn_rcpf(1.0f + e);
}
__device__ __forceinline__ unsigned short bfc(float x){
  return __builtin_bit_cast(unsigned short, (__bf16)x);
}

// ---------------- prep: weights -> bf16 MFMA-fragment layout in ws ----------------
__global__ __launch_bounds__(256) void k_prep(const float* __restrict__ bw1,
                                              const float* __restrict__ aw1,
                                              unsigned short* __restrict__ ws_wb,
                                              unsigned short* __restrict__ ws_wa)
{
  const int u = blockIdx.x*256 + threadIdx.x;
  if (u < 4096){
    const int lane = u & 63, ks = (u>>6)&7, nf = (u>>9)&1, widx = u>>10;
    const int c = lane & 15, g = lane >> 4;
    const int col = widx*32 + nf*16 + c;
    u16x8 t;
    #pragma unroll
    for (int e = 0; e < 8; ++e) t[e] = bfc(bw1[(ks*32 + g*8 + e)*128 + col]);
    *(u16x8*)&ws_wb[u*8] = t;
  } else if (u < 4096 + 1024){
    const int v = u - 4096;
    const int lane = v & 63, nf = (v>>6)&3, kt = v>>8;
    const int c = lane & 15, g = lane >> 4;
    const int col = nf*16 + c;
    u16x8 t;
    #pragma unroll
    for (int e = 0; e < 8; ++e) t[e] = bfc(aw1[(kt*32 + g*8 + e)*64 + col]);
    *(u16x8*)&ws_wa[v*8] = t;
  }
}

// ---------------- geometry + mean_acc zeroing ----------------
__global__ __launch_bounds__(256) void k_geom(const float* __restrict__ pose,
                                              float* __restrict__ out_aa,
                                              float* __restrict__ out_abl,
                                              float* __restrict__ mean_acc)
{
  __shared__ float sp[256*51];
  const int tid = threadIdx.x;
  const int fbase = blockIdx.x * 256;
  const int nfr = min(256, NF - fbase);

  for (int u = tid; u < nfr*51; u += 256) sp[u] = pose[(long)fbase*51 + u];
  for (long i = (long)blockIdx.x*256 + tid; i < 64L*JC; i += (long)gridDim.x*256)
    mean_acc[i] = 0.0f;
  __syncthreads();

  if (tid < nfr){
    const int f = fbase + tid;
    const float* p = sp + tid*51;
    float px[NJ], py[NJ], pz[NJ];
    #pragma unroll
    for (int j = 0; j < NJ; ++j){ px[j] = p[3*j]; py[j] = p[3*j+1]; pz[j] = p[3*j+2]; }

    #pragma unroll
    for (int i = 0; i < 15; ++i){
      const int a = cA[i], b = cB[i];
      const float dx = px[b]-px[a], dy = py[b]-py[a], dz = pz[b]-pz[a];
      out_abl[(long)f*15 + i] = sqrtf(dx*dx + dy*dy + dz*dz);
    }

    float ang[NJ];
    #pragma unroll
    for (int j = 0; j < NJ; ++j) ang[j] = 0.0f;
    #pragma unroll
    for (int i = 0; i < 4; ++i){
      const int jj = aJ[i], pp = aP[i], cc = aCc[i];
      float v1x = px[jj]-px[pp], v1y = py[jj]-py[pp], v1z = pz[jj]-pz[pp];
      float v2x = px[cc]-px[jj], v2y = py[cc]-py[jj], v2z = pz[cc]-pz[jj];
      const float n1 = sqrtf(v1x*v1x + v1y*v1y + v1z*v1z) + 1e-10f;
      const float n2 = sqrtf(v2x*v2x + v2y*v2y + v2z*v2z) + 1e-10f;
      v1x /= n1; v1y /= n1; v1z /= n1;
      v2x /= n2; v2y /= n2; v2z /= n2;
      float d = v1x*v2x + v1y*v2y + v1z*v2z;
      d = fminf(fmaxf(d, -1.0f + 1e-7f), 1.0f - 1e-7f);
      ang[jj] = acosf(d);
    }
    #pragma unroll
    for (int j = 0; j < NJ; ++j) out_aa[(long)f*NJ + j] = ang[j];
  }
}

// ---------------- cvt: feat f32 -> bf16 + fused mean, deep-ILP version ----------------
// 9 frames/block (batch-aligned). ALL loads issued before any dependent work:
// ~20 independent float4 loads/thread => ~20KB in flight per wave.
__global__ __launch_bounds__(256) void k_cvt(const float* __restrict__ feat,
                                             unsigned short* __restrict__ f16,
                                             float* __restrict__ mean_acc)
{
  const int tid = threadIdx.x;
  const long F0 = (long)blockIdx.x * 9;
  const int b = (int)(F0 / TT);
  const float* src = feat + F0*JC;
  unsigned short* dst = f16 + F0*JC;

  // ---- phase A: issue all loads ----
  float4 v0[9], v1[9];
  #pragma unroll
  for (int f = 0; f < 9; ++f){
    v0[f] = *(const float4*)(src + (long)f*JC + tid*8);
    v1[f] = *(const float4*)(src + (long)f*JC + tid*8 + 4);
  }
  const bool xok = (tid < 144);
  const int xf = tid >> 4, xu = 256 + (tid & 15);
  float4 x0, x1;
  if (xok){
    x0 = *(const float4*)(src + (long)xf*JC + xu*8);
    x1 = *(const float4*)(src + (long)xf*JC + xu*8 + 4);
  }

  // ---- phase B: mean + cvt + store ----
  float m[8] = {0.f,0.f,0.f,0.f,0.f,0.f,0.f,0.f};
  #pragma unroll
  for (int f = 0; f < 9; ++f){
    m[0]+=v0[f].x; m[1]+=v0[f].y; m[2]+=v0[f].z; m[3]+=v0[f].w;
    m[4]+=v1[f].x; m[5]+=v1[f].y; m[6]+=v1[f].z; m[7]+=v1[f].w;
    u16x8 q;
    q[0]=bfc(v0[f].x); q[1]=bfc(v0[f].y); q[2]=bfc(v0[f].z); q[3]=bfc(v0[f].w);
    q[4]=bfc(v1[f].x); q[5]=bfc(v1[f].y); q[6]=bfc(v1[f].z); q[7]=bfc(v1[f].w);
    *(u16x8*)&dst[(long)f*JC + tid*8] = q;
  }
  #pragma unroll
  for (int e = 0; e < 8; ++e)
    atomicAdd(&mean_acc[(long)b*JC + tid*8 + e], m[e]);

  if (xok){
    u16x8 q;
    q[0]=bfc(x0.x); q[1]=bfc(x0.y); q[2]=bfc(x0.z); q[3]=bfc(x0.w);
    q[4]=bfc(x1.x); q[5]=bfc(x1.y); q[6]=bfc(x1.z); q[7]=bfc(x1.w);
    *(u16x8*)&dst[(long)xf*JC + xu*8] = q;
    const float xm[8] = {x0.x,x0.y,x0.z,x0.w,x1.x,x1.y,x1.z,x1.w};
    #pragma unroll
    for (int e = 0; e < 8; ++e)
      atomicAdd(&mean_acc[(long)b*JC + xu*8 + e], xm[e]);
  }
}

// ---------------- fallback mean (f32 path): per-batch channel sums ----------------
__global__ __launch_bounds__(256) void k_mean(const float* __restrict__ feat,
                                              float* __restrict__ mean_acc)
{
  const int jc = blockIdx.x*256 + threadIdx.x;
  const int b = blockIdx.y;
  if (jc >= JC) return;
  float s = 0.0f;
  const float* p = feat + (long)b*TT*JC + jc;
  #pragma unroll 9
  for (int t = 0; t < TT; ++t) s += p[(long)t*JC];
  mean_acc[(long)b*JC + jc] = s;    // sum; k_action divides by 243
}

// ---------------- angle MLP: wave-autonomous, zero LDS, zero barriers ----------------
template<int BF>
__global__ __launch_bounds__(256) void k_angle(const void* __restrict__ srcv,
    const unsigned short* __restrict__ ws_wa,
    const float* __restrict__ ab1, const float* __restrict__ aw2,
    const float* __restrict__ ab2, float* __restrict__ out_pa)
{
  const int tid = threadIdx.x, w = tid >> 6, lane = tid & 63;
  const int g = lane >> 4, c = lane & 15;

  bf16x8 wa[4][4];
  #pragma unroll
  for (int kt = 0; kt < 4; ++kt)
    #pragma unroll
    for (int nf = 0; nf < 4; ++nf)
      wa[kt][nf] = __builtin_bit_cast(bf16x8, *(const u16x8*)&ws_wa[((kt*4 + nf)*64 + lane)*8]);

  float ab1c[4], aw2c[4][3];
  #pragma unroll
  for (int nf = 0; nf < 4; ++nf){
    const int col = nf*16 + c;
    ab1c[nf] = ab1[col];
    #pragma unroll
    for (int m = 0; m < 3; ++m) aw2c[nf][m] = aw2[col*3 + m];
  }
  const float ab2c[3] = {ab2[0], ab2[1], ab2[2]};

  const long rbase = (long)blockIdx.x*192 + w*48;
  #pragma unroll
  for (int i = 0; i < 3; ++i){
    const long r0 = rbase + i*16;
    f32x4 acc[4];
    #pragma unroll
    for (int nf = 0; nf < 4; ++nf) acc[nf] = (f32x4)0.0f;

    #pragma unroll
    for (int kt = 0; kt < 4; ++kt){
      bf16x8 av;
      if (BF){
        const unsigned short* sp = (const unsigned short*)srcv + (r0 + c)*NC + kt*32 + g*8;
        av = __builtin_bit_cast(bf16x8, *(const u16x8*)sp);
      } else {
        const float* sp = (const float*)srcv + (r0 + c)*NC + kt*32 + g*8;
        const float4 a0 = *(const float4*)sp;
        const float4 a1 = *(const float4*)(sp + 4);
        u16x8 t;
        t[0]=bfc(a0.x); t[1]=bfc(a0.y); t[2]=bfc(a0.z); t[3]=bfc(a0.w);
        t[4]=bfc(a1.x); t[5]=bfc(a1.y); t[6]=bfc(a1.z); t[7]=bfc(a1.w);
        av = __builtin_bit_cast(bf16x8, t);
      }
      #pragma unroll
      for (int nf = 0; nf < 4; ++nf)
        acc[nf] = __builtin_amdgcn_mfma_f32_16x16x32_bf16(av, wa[kt][nf], acc[nf], 0, 0, 0);
    }

    float s[4][3];
    #pragma unroll
    for (int r = 0; r < 4; ++r){ s[r][0]=0.f; s[r][1]=0.f; s[r][2]=0.f; }
    #pragma unroll
    for (int nf = 0; nf < 4; ++nf)
      #pragma unroll
      for (int r = 0; r < 4; ++r){
        const float h = gelu_fast(acc[nf][r] + ab1c[nf]);
        s[r][0] = fmaf(h, aw2c[nf][0], s[r][0]);
        s[r][1] = fmaf(h, aw2c[nf][1], s[r][1]);
        s[r][2] = fmaf(h, aw2c[nf][2], s[r][2]);
      }
    #pragma unroll
    for (int r = 0; r < 4; ++r)
      #pragma unroll
      for (int m = 0; m < 3; ++m){
        float v = s[r][m];
        v += __shfl_xor(v, 1);
        v += __shfl_xor(v, 2);
        v += __shfl_xor(v, 4);
        v += __shfl_xor(v, 8);
        s[r][m] = v;
      }
    if (c == 0){
      #pragma unroll
      for (int r = 0; r < 4; ++r){
        const long row = r0 + g*4 + r;
        #pragma unroll
        for (int m = 0; m < 3; ++m)
          out_pa[row*3 + m] = s[r][m] + ab2c[m];
      }
    }
  }
}

// ---------------- bone MLP: one wave = one frame, 2-deep load pipeline ----------------
template<int BF>
__global__ __launch_bounds__(256) void k_bone(const void* __restrict__ srcv,
    const unsigned short* __restrict__ ws_wb,
    const float* __restrict__ bb1, const float* __restrict__ bw2,
    const float* __restrict__ bb2, float* __restrict__ out_pbl)
{
  const int tid = threadIdx.x, w = tid >> 6, lane = tid & 63;
  const int g = lane >> 4, c = lane & 15;

  float bb1c[8], bw2c[8];
  #pragma unroll
  for (int P = 0; P < 8; ++P){ bb1c[P] = bb1[P*16 + c]; bw2c[P] = bw2[P*16 + c]; }
  const float bb2c = bb2[0];
  const int jAo = d_cA16[c]*NC, jBo = d_cB16[c]*NC;

  auto loadA = [&](bf16x8 (&af)[8], long frame){
    if (BF){
      const unsigned short* fb = (const unsigned short*)srcv + frame*JC;
      #pragma unroll
      for (int ks = 0; ks < 8; ++ks)
        af[ks] = __builtin_bit_cast(bf16x8,
            *(const u16x8*)&fb[(ks < 4 ? jAo : jBo) + (ks & 3)*32 + g*8]);
    } else {
      const float* fb = (const float*)srcv + frame*JC;
      #pragma unroll
      for (int ks = 0; ks < 8; ++ks){
        const float* pa = fb + (ks < 4 ? jAo : jBo) + (ks & 3)*32 + g*8;
        const float4 a0 = *(const float4*)pa;
        const float4 a1 = *(const float4*)(pa + 4);
        u16x8 t;
        t[0]=bfc(a0.x); t[1]=bfc(a0.y); t[2]=bfc(a0.z); t[3]=bfc(a0.w);
        t[4]=bfc(a1.x); t[5]=bfc(a1.y); t[6]=bfc(a1.z); t[7]=bfc(a1.w);
        af[ks] = __builtin_bit_cast(bf16x8, t);
      }
    }
  };

  const long fbase = (long)blockIdx.x*12 + w*3;
  bf16x8 af[8];
  loadA(af, fbase);

  #pragma unroll
  for (int i = 0; i < 3; ++i){
    const long frame = fbase + i;
    bf16x8 afn[8];
    if (i < 2) loadA(afn, frame + 1);    // in flight during compute below

    float s[4] = {0.f, 0.f, 0.f, 0.f};
    #pragma unroll
    for (int nfp = 0; nfp < 4; ++nfp){
      f32x4 acc0 = (f32x4)0.0f, acc1 = (f32x4)0.0f;
      #pragma unroll
      for (int ks = 0; ks < 8; ++ks){
        const bf16x8 wb0 = __builtin_bit_cast(bf16x8,
            *(const u16x8*)&ws_wb[(((nfp*2 + 0)*8 + ks)*64 + lane)*8]);
        const bf16x8 wb1 = __builtin_bit_cast(bf16x8,
            *(const u16x8*)&ws_wb[(((nfp*2 + 1)*8 + ks)*64 + lane)*8]);
        acc0 = __builtin_amdgcn_mfma_f32_16x16x32_bf16(af[ks], wb0, acc0, 0, 0, 0);
        acc1 = __builtin_amdgcn_mfma_f32_16x16x32_bf16(af[ks], wb1, acc1, 0, 0, 0);
      }
      #pragma unroll
      for (int r = 0; r < 4; ++r)
        s[r] += gelu_fast(acc0[r] + bb1c[nfp*2    ]) * bw2c[nfp*2    ]
              + gelu_fast(acc1[r] + bb1c[nfp*2 + 1]) * bw2c[nfp*2 + 1];
    }
    #pragma unroll
    for (int r = 0; r < 4; ++r){
      s[r] += __shfl_xor(s[r], 1);
      s[r] += __shfl_xor(s[r], 2);
      s[r] += __shfl_xor(s[r], 4);
      s[r] += __shfl_xor(s[r], 8);
    }
    if (c == 0){
      #pragma unroll
      for (int r = 0; r < 4; ++r){
        const int bone = g*4 + r;
        if (bone < 15)
          out_pbl[frame*15 + bone] = fmaxf(s[r] + bb2c, 0.0f);
      }
    }
    #pragma unroll
    for (int ks = 0; ks < 8; ++ks) af[ks] = afn[ks];
  }
}

// ---------------- action classifier (reads per-batch sums) ----------------
__global__ __launch_bounds__(256) void k_action(const float* __restrict__ sum_src,
    const float* __restrict__ cw1, const float* __restrict__ cb1,
    const float* __restrict__ cw2, const float* __restrict__ cb2,
    float* __restrict__ out_lg)
{
  __shared__ float s_m[JC];
  __shared__ float s_part[4][64];
  __shared__ float s_h[64];
  const int b = blockIdx.x, tid = threadIdx.x;
  for (int i = tid; i < JC; i += 256) s_m[i] = sum_src[(long)b*JC + i] * (1.0f/243.0f);
  __syncthreads();
  const int n = tid & 63, part = tid >> 6;
  float s = 0.0f;
  const int k0 = part * 544;
  for (int k = k0; k < k0 + 544; ++k) s = fmaf(s_m[k], cw1[(long)k*64 + n], s);
  s_part[part][n] = s;
  __syncthreads();
  if (tid < 64) s_h[tid] = gelu_exact(s_part[0][tid] + s_part[1][tid] +
                                      s_part[2][tid] + s_part[3][tid] + cb1[tid]);
  __syncthreads();
  if (tid < 8){
    float v = cb2[tid];
    #pragma unroll
    for (int k = 0; k < 64; ++k) v = fmaf(s_h[k], cw2[k*8 + tid], v);
    out_lg[b*8 + tid] = v;
  }
}

extern "C" void kernel_launch(void* const* d_in, const int* in_sizes, int n_in,
                              void* d_out, int out_size, void* d_ws, size_t ws_size,
                              hipStream_t stream)
{
  const float* feat = (const float*)d_in[0];
  const float* pose = (const float*)d_in[1];
  const float* aw1  = (const float*)d_in[2];
  const float* ab1  = (const float*)d_in[3];
  const float* aw2  = (const float*)d_in[4];
  const float* ab2  = (const float*)d_in[5];
  const float* bw1  = (const float*)d_in[6];
  const float* bb1  = (const float*)d_in[7];
  const float* bw2  = (const float*)d_in[8];
  const float* bb2  = (const float*)d_in[9];
  const float* cw1  = (const float*)d_in[10];
  const float* cb1  = (const float*)d_in[11];
  const float* cw2  = (const float*)d_in[12];
  const float* cb2  = (const float*)d_in[13];

  float* out = (float*)d_out;
  float* out_pa  = out;                 // [NF,17,3]  793152
  float* out_aa  = out + 793152;        // [NF,17,1]  264384
  float* out_pbl = out + 1057536;       // [NF,15,1]  233280
  float* out_abl = out + 1290816;       // [NF,15,1]  233280
  float* out_lg  = out + 1524096;       // [64,8]     512

  float* mean_acc = (float*)d_ws;
  unsigned short* ws_wb  = (unsigned short*)((char*)d_ws + WSO_WB);
  unsigned short* ws_wa  = (unsigned short*)((char*)d_ws + WSO_WA);
  unsigned short* ws_f16 = (unsigned short*)((char*)d_ws + WSO_F16);

  const bool useBF = (ws_size >= WS_NEED);

  k_prep<<<dim3(20), dim3(256), 0, stream>>>(bw1, aw1, ws_wb, ws_wa);
  k_geom<<<dim3((NF + 255)/256), dim3(256), 0, stream>>>(pose, out_aa, out_abl, mean_acc);

  if (useBF){
    k_cvt<<<dim3(NF/9), dim3(256), 0, stream>>>(feat, ws_f16, mean_acc);
    k_angle<1><<<dim3((NF*NJ)/192), dim3(256), 0, stream>>>(ws_f16, ws_wa, ab1, aw2, ab2, out_pa);
    k_bone<1><<<dim3(NF/12), dim3(256), 0, stream>>>(ws_f16, ws_wb, bb1, bw2, bb2, out_pbl);
  } else {
    k_mean<<<dim3((JC + 255)/256, 64), dim3(256), 0, stream>>>(feat, mean_acc);
    k_angle<0><<<dim3((NF*NJ)/192), dim3(256), 0, stream>>>(feat, ws_wa, ab1, aw2, ab2, out_pa);
    k_bone<0><<<dim3(NF/12), dim3(256), 0, stream>>>(feat, ws_wb, bb1, bw2, bb2, out_pbl);
  }

  k_action<<<dim3(64), dim3(256), 0, stream>>>(mean_acc, cw1, cb1, cw2, cb2, out_lg);
}

// Round 13
// 158.073 us; speedup vs baseline: 2.8351x; 2.8351x over previous
//
#include <hip/hip_runtime.h>
#include <math.h>

#define NF 15552      // B*T
#define NJ 17
#define NC 128
#define JC (NJ*NC)    // 2176
#define TT 243        // frames per batch
#define FB 4          // frames per iteration
#define NIT 4         // iterations per block  (R4 had 16; ONLY change this round)
#define FRB (FB*NIT)  // 16 frames per block; grid = 972 (~3.8 blocks/CU, 3 resident)

constexpr int cA[15] = {0,1,2,0,4,5,0,7,8,0,10,11,0,13,14};
constexpr int cB[15] = {1,2,3,4,5,6,7,8,9,10,11,12,13,14,15};
constexpr int aJ[4] = {11,14,5,8};
constexpr int aP[4] = {10,13,4,7};
constexpr int aCc[4] = {12,15,6,9};

__device__ const int d_cA16[16] = {0,1,2,0,4,5,0,7,8,0,10,11,0,13,14,0};
__device__ const int d_cB16[16] = {1,2,3,4,5,6,7,8,9,10,11,12,13,14,15,0};

typedef __bf16 bf16x8 __attribute__((ext_vector_type(8)));
typedef float f32x4 __attribute__((ext_vector_type(4)));
typedef unsigned short u16x8 __attribute__((ext_vector_type(8)));

__device__ __forceinline__ float gelu_exact(float x){
  return 0.5f * x * (1.0f + erff(x * 0.7071067811865476f));
}
// tanh-form gelu; |err vs exact| <= ~3e-3
__device__ __forceinline__ float gelu_fast(float x){
  const float s2 = x * x;
  const float q  = fmaf(s2, -0.1029437f, -2.3021183f);
  const float e  = __builtin_amdgcn_exp2f(q * x);
  return x * __builtin_amdgcn_rcpf(1.0f + e);
}
__device__ __forceinline__ unsigned short bfc(float x){
  return __builtin_bit_cast(unsigned short, (__bf16)x);
}
__device__ __forceinline__ float bf2f(unsigned short u){
  return __builtin_bit_cast(float, ((unsigned)u) << 16);
}

// ---------------- geometry + mean_acc zeroing ----------------
__global__ __launch_bounds__(256) void k_geom(const float* __restrict__ pose,
                                              float* __restrict__ out_aa,
                                              float* __restrict__ out_abl,
                                              float* __restrict__ mean_acc)
{
  for (long i = (long)blockIdx.x*256 + threadIdx.x; i < 64L*JC; i += (long)gridDim.x*256)
    mean_acc[i] = 0.0f;

  const int f = blockIdx.x * 256 + threadIdx.x;
  if (f >= NF) return;
  const float* p = pose + (long)f * NJ * 3;
  float px[NJ], py[NJ], pz[NJ];
  #pragma unroll
  for (int j = 0; j < NJ; ++j){ px[j] = p[3*j]; py[j] = p[3*j+1]; pz[j] = p[3*j+2]; }

  #pragma unroll
  for (int i = 0; i < 15; ++i){
    const int a = cA[i], b = cB[i];
    const float dx = px[b]-px[a], dy = py[b]-py[a], dz = pz[b]-pz[a];
    out_abl[(long)f*15 + i] = sqrtf(dx*dx + dy*dy + dz*dz);
  }

  float ang[NJ];
  #pragma unroll
  for (int j = 0; j < NJ; ++j) ang[j] = 0.0f;
  #pragma unroll
  for (int i = 0; i < 4; ++i){
    const int jj = aJ[i], pp = aP[i], cc = aCc[i];
    float v1x = px[jj]-px[pp], v1y = py[jj]-py[pp], v1z = pz[jj]-pz[pp];
    float v2x = px[cc]-px[jj], v2y = py[cc]-py[jj], v2z = pz[cc]-pz[jj];
    const float n1 = sqrtf(v1x*v1x + v1y*v1y + v1z*v1z) + 1e-10f;
    const float n2 = sqrtf(v2x*v2x + v2y*v2y + v2z*v2z) + 1e-10f;
    v1x /= n1; v1y /= n1; v1z /= n1;
    v2x /= n2; v2y /= n2; v2z /= n2;
    float d = v1x*v2x + v1y*v2y + v1z*v2z;
    d = fminf(fmaxf(d, -1.0f + 1e-7f), 1.0f - 1e-7f);
    ang[jj] = acosf(d);
  }
  #pragma unroll
  for (int j = 0; j < NJ; ++j) out_aa[(long)f*NJ + j] = ang[j];
}

// ---------------- fused: angle MLP + bone MLP + mean partial ----------------
// LDS: double-buffered FB frames x 17 x 128 bf16, 16B blocks swizzled kb^(j&7).
#define SFO(fi, off16) (((fi)*272 + (off16))*8)

__global__ __launch_bounds__(256, 1) void k_fused(const float* __restrict__ feat,
    const float* __restrict__ aw1, const float* __restrict__ ab1,
    const float* __restrict__ aw2, const float* __restrict__ ab2,
    const float* __restrict__ bw1, const float* __restrict__ bb1,
    const float* __restrict__ bw2, const float* __restrict__ bb2,
    float* __restrict__ out_pa, float* __restrict__ out_pbl,
    float* __restrict__ mean_acc)
{
  __shared__ __align__(16) unsigned short s_feat[2][FB*NJ*NC];  // 2x17408 B
  __shared__ float s_red[4][FB][16];                            // 1 KB

  const int tid  = threadIdx.x;
  const int w    = tid >> 6;
  const int lane = tid & 63;
  const int g    = lane >> 4;       // k-group
  const int c    = lane & 15;       // A-row / B,D-col within fragment
  const long F0  = (long)blockIdx.x * FRB;

  auto stage = [&](int bsel, int it){
    const float* base = feat + (F0 + (long)it*FB) * JC;
    unsigned short* dst = s_feat[bsel];
    #pragma unroll
    for (int u0 = 0; u0 < FB*272; u0 += 256){
      const int u = u0 + tid;
      if (u < FB*272){
        const float4 v0 = *(const float4*)(base + u*8);
        const float4 v1 = *(const float4*)(base + u*8 + 4);
        u16x8 p;
        p[0]=bfc(v0.x); p[1]=bfc(v0.y); p[2]=bfc(v0.z); p[3]=bfc(v0.w);
        p[4]=bfc(v1.x); p[5]=bfc(v1.y); p[6]=bfc(v1.z); p[7]=bfc(v1.w);
        const int fi = u / 272, r = u - fi*272;
        const int j = r >> 4, kb = r & 15;
        *(u16x8*)&dst[SFO(fi, j*16 + (kb ^ (j & 7)))] = p;
      }
    }
  };

  stage(0, 0);

  // ---- bone weight fragments (bw1 [256][128]) ----
  bf16x8 wb[8][2];
  float bb1c[2], bw2c[2];
  #pragma unroll
  for (int nf = 0; nf < 2; ++nf){
    const int col = w*32 + nf*16 + c;
    bb1c[nf] = bb1[col];
    bw2c[nf] = bw2[col];
    #pragma unroll
    for (int ks = 0; ks < 8; ++ks){
      u16x8 t;
      #pragma unroll
      for (int e = 0; e < 8; ++e) t[e] = bfc(bw1[(ks*32 + g*8 + e)*128 + col]);
      wb[ks][nf] = __builtin_bit_cast(bf16x8, t);
    }
  }
  // ---- angle weight fragments (aw1 [128][64]) ----
  bf16x8 wa[4][4];
  float ab1c[4], aw2c[4][3];
  #pragma unroll
  for (int nf = 0; nf < 4; ++nf){
    const int col = nf*16 + c;
    ab1c[nf] = ab1[col];
    #pragma unroll
    for (int m = 0; m < 3; ++m) aw2c[nf][m] = aw2[col*3 + m];
    #pragma unroll
    for (int kt = 0; kt < 4; ++kt){
      u16x8 t;
      #pragma unroll
      for (int e = 0; e < 8; ++e) t[e] = bfc(aw1[(kt*32 + g*8 + e)*64 + col]);
      wa[kt][nf] = __builtin_bit_cast(bf16x8, t);
    }
  }
  const float ab2c[3] = {ab2[0], ab2[1], ab2[2]};
  const float bb2c = bb2[0];

  // ---- bone A-fragment block offsets (swizzled) ----
  const int jA = d_cA16[c], jB = d_cB16[c];
  int boff[8];
  #pragma unroll
  for (int ks = 0; ks < 8; ++ks){
    const int kk = ks*32 + g*8;
    const int j  = (kk < 128) ? jA : jB;
    const int kb = (kk < 128) ? (ks*4 + g) : (ks*4 + g - 16);
    boff[ks] = j*16 + (kb ^ (j & 7));
  }

  // ---- mean accumulators (batch-split) ----
  const int b0    = (int)(F0 / TT);
  const int split = min(FRB, TT - (int)(F0 - (long)b0*TT));   // frames in batch b0
  float m0[9], m1[9];
  #pragma unroll
  for (int s = 0; s < 9; ++s){ m0[s] = 0.f; m1[s] = 0.f; }

  int buf = 0;
  for (int it = 0; it < NIT; ++it){
    __syncthreads();                       // staged buf ready; s_red free
    if (it + 1 < NIT) stage(buf ^ 1, it + 1);

    const unsigned short* fb = s_feat[buf];

    // ---- bone MFMA: all FB frames, this wave's 32 cols ----
    f32x4 bacc[FB][2];
    #pragma unroll
    for (int fi = 0; fi < FB; ++fi){ bacc[fi][0] = (f32x4)0.0f; bacc[fi][1] = (f32x4)0.0f; }
    #pragma unroll
    for (int ks = 0; ks < 8; ++ks){
      bf16x8 av[FB];
      #pragma unroll
      for (int fi = 0; fi < FB; ++fi)
        av[fi] = __builtin_bit_cast(bf16x8, *(const u16x8*)&fb[SFO(fi, boff[ks])]);
      #pragma unroll
      for (int fi = 0; fi < FB; ++fi){
        bacc[fi][0] = __builtin_amdgcn_mfma_f32_16x16x32_bf16(av[fi], wb[ks][0], bacc[fi][0], 0, 0, 0);
        bacc[fi][1] = __builtin_amdgcn_mfma_f32_16x16x32_bf16(av[fi], wb[ks][1], bacc[fi][1], 0, 0, 0);
      }
    }
    #pragma unroll
    for (int fi = 0; fi < FB; ++fi){
      float s[4] = {0.f, 0.f, 0.f, 0.f};
      #pragma unroll
      for (int nf = 0; nf < 2; ++nf)
        #pragma unroll
        for (int r = 0; r < 4; ++r)
          s[r] += gelu_fast(bacc[fi][nf][r] + bb1c[nf]) * bw2c[nf];
      #pragma unroll
      for (int r = 0; r < 4; ++r){
        s[r] += __shfl_xor(s[r], 1);
        s[r] += __shfl_xor(s[r], 2);
        s[r] += __shfl_xor(s[r], 4);
        s[r] += __shfl_xor(s[r], 8);
      }
      if (c == 0)
        #pragma unroll
        for (int r = 0; r < 4; ++r) s_red[w][fi][g*4 + r] = s[r];
    }

    // ---- angle MFMA: wave w -> frame w (16 joints); w0 also joint-16 rows ----
    f32x4 acc0[4], accj[4];
    #pragma unroll
    for (int nf = 0; nf < 4; ++nf){ acc0[nf]=(f32x4)0.0f; accj[nf]=(f32x4)0.0f; }
    #pragma unroll
    for (int kt = 0; kt < 4; ++kt){
      const int kbx = kt*4 + g;
      const bf16x8 av0 = __builtin_bit_cast(bf16x8,
          *(const u16x8*)&fb[SFO(w, c*16 + (kbx ^ (c & 7)))]);
      #pragma unroll
      for (int nf = 0; nf < 4; ++nf)
        acc0[nf] = __builtin_amdgcn_mfma_f32_16x16x32_bf16(av0, wa[kt][nf], acc0[nf], 0, 0, 0);
      if (w == 0){
        const bf16x8 avj = __builtin_bit_cast(bf16x8,
            *(const u16x8*)&fb[SFO(c & 3, 16*16 + kbx)]);   // joint 16 (j&7==0)
        #pragma unroll
        for (int nf = 0; nf < 4; ++nf)
          accj[nf] = __builtin_amdgcn_mfma_f32_16x16x32_bf16(avj, wa[kt][nf], accj[nf], 0, 0, 0);
      }
    }
    {
      float s[4][3];
      #pragma unroll
      for (int r = 0; r < 4; ++r){ s[r][0]=0.f; s[r][1]=0.f; s[r][2]=0.f; }
      #pragma unroll
      for (int nf = 0; nf < 4; ++nf)
        #pragma unroll
        for (int r = 0; r < 4; ++r){
          const float h = gelu_fast(acc0[nf][r] + ab1c[nf]);
          s[r][0] = fmaf(h, aw2c[nf][0], s[r][0]);
          s[r][1] = fmaf(h, aw2c[nf][1], s[r][1]);
          s[r][2] = fmaf(h, aw2c[nf][2], s[r][2]);
        }
      #pragma unroll
      for (int r = 0; r < 4; ++r)
        #pragma unroll
        for (int m = 0; m < 3; ++m){
          float v = s[r][m];
          v += __shfl_xor(v, 1);
          v += __shfl_xor(v, 2);
          v += __shfl_xor(v, 4);
          v += __shfl_xor(v, 8);
          s[r][m] = v;
        }
      if (c == 0){
        const long frame = F0 + (long)it*FB + w;
        #pragma unroll
        for (int r = 0; r < 4; ++r){
          const int joint = g*4 + r;
          #pragma unroll
          for (int m = 0; m < 3; ++m)
            out_pa[(frame*NJ + joint)*3 + m] = s[r][m] + ab2c[m];
        }
      }
    }
    if (w == 0){
      float s[4][3];
      #pragma unroll
      for (int r = 0; r < 4; ++r){ s[r][0]=0.f; s[r][1]=0.f; s[r][2]=0.f; }
      #pragma unroll
      for (int nf = 0; nf < 4; ++nf)
        #pragma unroll
        for (int r = 0; r < 4; ++r){
          const float h = gelu_fast(accj[nf][r] + ab1c[nf]);
          s[r][0] = fmaf(h, aw2c[nf][0], s[r][0]);
          s[r][1] = fmaf(h, aw2c[nf][1], s[r][1]);
          s[r][2] = fmaf(h, aw2c[nf][2], s[r][2]);
        }
      #pragma unroll
      for (int r = 0; r < 4; ++r)
        #pragma unroll
        for (int m = 0; m < 3; ++m){
          float v = s[r][m];
          v += __shfl_xor(v, 1);
          v += __shfl_xor(v, 2);
          v += __shfl_xor(v, 4);
          v += __shfl_xor(v, 8);
          s[r][m] = v;
        }
      if (c == 0 && g == 0){
        #pragma unroll
        for (int r = 0; r < 4; ++r){     // r = frame within iter
          const long frame = F0 + (long)it*FB + r;
          #pragma unroll
          for (int m = 0; m < 3; ++m)
            out_pa[(frame*NJ + 16)*3 + m] = s[r][m] + ab2c[m];
        }
      }
    }

    // ---- mean accumulate from staged tile ----
    #pragma unroll
    for (int s = 0; s < 9; ++s){
      const int jc = tid + s*256;
      if (jc < JC){
        const int j = jc >> 7, k = jc & 127;
        const int eoff = (j*16 + ((k >> 3) ^ (j & 7)))*8 + (k & 7);
        #pragma unroll
        for (int fi = 0; fi < FB; ++fi){
          const float v = bf2f(fb[fi*JC + eoff]);
          if (it*FB + fi < split) m0[s] += v; else m1[s] += v;
        }
      }
    }

    __syncthreads();                     // s_red complete
    if (tid < FB*15){
      const int fi = tid / 15, row = tid - fi*15;
      const float v = s_red[0][fi][row] + s_red[1][fi][row] +
                      s_red[2][fi][row] + s_red[3][fi][row] + bb2c;
      out_pbl[(F0 + (long)it*FB + fi)*15 + row] = fmaxf(v, 0.0f);
    }
    buf ^= 1;
  }

  // ---- mean flush: one atomic per (batch, jc) ----
  #pragma unroll
  for (int s = 0; s < 9; ++s){
    const int jc = tid + s*256;
    if (jc < JC){
      atomicAdd(&mean_acc[(long)b0*JC + jc], m0[s]);
      if (split < FRB) atomicAdd(&mean_acc[(long)(b0+1)*JC + jc], m1[s]);
    }
  }
}

// ---------------- action classifier (reads per-batch sums) ----------------
__global__ __launch_bounds__(256) void k_action(const float* __restrict__ sum_src,
    const float* __restrict__ cw1, const float* __restrict__ cb1,
    const float* __restrict__ cw2, const float* __restrict__ cb2,
    float* __restrict__ out_lg)
{
  __shared__ float s_m[JC];
  __shared__ float s_part[4][64];
  __shared__ float s_h[64];
  const int b = blockIdx.x, tid = threadIdx.x;
  for (int i = tid; i < JC; i += 256) s_m[i] = sum_src[(long)b*JC + i] * (1.0f/243.0f);
  __syncthreads();
  const int n = tid & 63, part = tid >> 6;
  float s = 0.0f;
  const int k0 = part * 544;
  for (int k = k0; k < k0 + 544; ++k) s = fmaf(s_m[k], cw1[(long)k*64 + n], s);
  s_part[part][n] = s;
  __syncthreads();
  if (tid < 64) s_h[tid] = gelu_exact(s_part[0][tid] + s_part[1][tid] +
                                      s_part[2][tid] + s_part[3][tid] + cb1[tid]);
  __syncthreads();
  if (tid < 8){
    float v = cb2[tid];
    #pragma unroll
    for (int k = 0; k < 64; ++k) v = fmaf(s_h[k], cw2[k*8 + tid], v);
    out_lg[b*8 + tid] = v;
  }
}

extern "C" void kernel_launch(void* const* d_in, const int* in_sizes, int n_in,
                              void* d_out, int out_size, void* d_ws, size_t ws_size,
                              hipStream_t stream)
{
  const float* feat = (const float*)d_in[0];
  const float* pose = (const float*)d_in[1];
  const float* aw1  = (const float*)d_in[2];
  const float* ab1  = (const float*)d_in[3];
  const float* aw2  = (const float*)d_in[4];
  const float* ab2  = (const float*)d_in[5];
  const float* bw1  = (const float*)d_in[6];
  const float* bb1  = (const float*)d_in[7];
  const float* bw2  = (const float*)d_in[8];
  const float* bb2  = (const float*)d_in[9];
  const float* cw1  = (const float*)d_in[10];
  const float* cb1  = (const float*)d_in[11];
  const float* cw2  = (const float*)d_in[12];
  const float* cb2  = (const float*)d_in[13];

  float* out = (float*)d_out;
  float* out_pa  = out;                 // [NF,17,3]  793152
  float* out_aa  = out + 793152;        // [NF,17,1]  264384
  float* out_pbl = out + 1057536;       // [NF,15,1]  233280
  float* out_abl = out + 1290816;       // [NF,15,1]  233280
  float* out_lg  = out + 1524096;       // [64,8]     512

  float* mean_acc = (float*)d_ws;       // 64*JC f32

  k_geom<<<dim3((NF + 255)/256), dim3(256), 0, stream>>>(pose, out_aa, out_abl, mean_acc);
  k_fused<<<dim3(NF/FRB), dim3(256), 0, stream>>>(feat, aw1, ab1, aw2, ab2,
                                                  bw1, bb1, bw2, bb2,
                                                  out_pa, out_pbl, mean_acc);
  k_action<<<dim3(64), dim3(256), 0, stream>>>(mean_acc, cw1, cb1, cw2, cb2, out_lg);
}

// Round 14
// 156.442 us; speedup vs baseline: 2.8647x; 1.0104x over previous
//
#include <hip/hip_runtime.h>
#include <math.h>

#define NF 15552      // B*T
#define NJ 17
#define NC 128
#define JC 2176       // NJ*NC
#define TT 243        // frames per batch

constexpr int cA[15] = {0,1,2,0,4,5,0,7,8,0,10,11,0,13,14};
constexpr int cB[15] = {1,2,3,4,5,6,7,8,9,10,11,12,13,14,15};
constexpr int aJ[4] = {11,14,5,8};
constexpr int aP[4] = {10,13,4,7};
constexpr int aCc[4] = {12,15,6,9};

__device__ const int d_cA16[16] = {0,1,2,0,4,5,0,7,8,0,10,11,0,13,14,0};
__device__ const int d_cB16[16] = {1,2,3,4,5,6,7,8,9,10,11,12,13,14,15,0};

typedef __bf16 bf16x8 __attribute__((ext_vector_type(8)));
typedef float f32x4 __attribute__((ext_vector_type(4)));
typedef unsigned short u16x8 __attribute__((ext_vector_type(8)));

// ws layout (bytes): [0) mean_acc 64*JC f32 | [557056) wb frags 65536 | [622592) wa frags 16384
#define WSO_WB  557056
#define WSO_WA  622592

__device__ __forceinline__ float gelu_exact(float x){
  return 0.5f * x * (1.0f + erff(x * 0.7071067811865476f));
}
__device__ __forceinline__ float gelu_fast(float x){
  const float s2 = x * x;
  const float q  = fmaf(s2, -0.1029437f, -2.3021183f);
  const float e  = __builtin_amdgcn_exp2f(q * x);
  return x * __builtin_amdgcn_rcpf(1.0f + e);
}
__device__ __forceinline__ unsigned short bfc(float x){
  return __builtin_bit_cast(unsigned short, (__bf16)x);
}

// ---------------- prep: weights -> bf16 MFMA-fragment layout in ws ----------------
__global__ __launch_bounds__(256) void k_prep(const float* __restrict__ bw1,
                                              const float* __restrict__ aw1,
                                              unsigned short* __restrict__ ws_wb,
                                              unsigned short* __restrict__ ws_wa)
{
  const int u = blockIdx.x*256 + threadIdx.x;
  if (u < 4096){
    const int lane = u & 63, ks = (u>>6)&7, nf = (u>>9)&1, widx = u>>10;
    const int c = lane & 15, g = lane >> 4;
    const int col = widx*32 + nf*16 + c;
    u16x8 t;
    #pragma unroll
    for (int e = 0; e < 8; ++e) t[e] = bfc(bw1[(ks*32 + g*8 + e)*128 + col]);
    *(u16x8*)&ws_wb[u*8] = t;
  } else if (u < 4096 + 1024){
    const int v = u - 4096;
    const int lane = v & 63, nf = (v>>6)&3, kt = v>>8;
    const int c = lane & 15, g = lane >> 4;
    const int col = nf*16 + c;
    u16x8 t;
    #pragma unroll
    for (int e = 0; e < 8; ++e) t[e] = bfc(aw1[(kt*32 + g*8 + e)*64 + col]);
    *(u16x8*)&ws_wa[v*8] = t;
  }
}

// ---------------- geometry ----------------
__global__ __launch_bounds__(256) void k_geom(const float* __restrict__ pose,
                                              float* __restrict__ out_aa,
                                              float* __restrict__ out_abl)
{
  __shared__ float sp[256*51];
  const int tid = threadIdx.x;
  const int fbase = blockIdx.x * 256;
  const int nfr = min(256, NF - fbase);

  for (int u = tid; u < nfr*51; u += 256) sp[u] = pose[(long)fbase*51 + u];
  __syncthreads();

  if (tid < nfr){
    const int f = fbase + tid;
    const float* p = sp + tid*51;
    float px[NJ], py[NJ], pz[NJ];
    #pragma unroll
    for (int j = 0; j < NJ; ++j){ px[j] = p[3*j]; py[j] = p[3*j+1]; pz[j] = p[3*j+2]; }

    #pragma unroll
    for (int i = 0; i < 15; ++i){
      const int a = cA[i], b = cB[i];
      const float dx = px[b]-px[a], dy = py[b]-py[a], dz = pz[b]-pz[a];
      out_abl[(long)f*15 + i] = sqrtf(dx*dx + dy*dy + dz*dz);
    }

    float ang[NJ];
    #pragma unroll
    for (int j = 0; j < NJ; ++j) ang[j] = 0.0f;
    #pragma unroll
    for (int i = 0; i < 4; ++i){
      const int jj = aJ[i], pp = aP[i], cc = aCc[i];
      float v1x = px[jj]-px[pp], v1y = py[jj]-py[pp], v1z = pz[jj]-pz[pp];
      float v2x = px[cc]-px[jj], v2y = py[cc]-py[jj], v2z = pz[cc]-pz[jj];
      const float n1 = sqrtf(v1x*v1x + v1y*v1y + v1z*v1z) + 1e-10f;
      const float n2 = sqrtf(v2x*v2x + v2y*v2y + v2z*v2z) + 1e-10f;
      v1x /= n1; v1y /= n1; v1z /= n1;
      v2x /= n2; v2y /= n2; v2z /= n2;
      float d = v1x*v2x + v1y*v2y + v1z*v2z;
      d = fminf(fmaxf(d, -1.0f + 1e-7f), 1.0f - 1e-7f);
      ang[jj] = acosf(d);
    }
    #pragma unroll
    for (int j = 0; j < NJ; ++j) out_aa[(long)f*NJ + j] = ang[j];
  }
}

// ---------------- mean: per-batch channel sums (direct store, no atomics) ----------------
// grid = (JC/256 rounded, 64). Thread owns one (b, jc); 243 independent strided loads.
__global__ __launch_bounds__(256) void k_mean(const float* __restrict__ feat,
                                              float* __restrict__ mean_acc)
{
  const int jc = blockIdx.x*256 + threadIdx.x;
  const int b = blockIdx.y;
  if (jc >= JC) return;
  const float* p = feat + (long)b*TT*JC + jc;
  float s = 0.0f;
  #pragma unroll 9
  for (int t = 0; t < TT; ++t) s += p[(long)t*JC];
  mean_acc[(long)b*JC + jc] = s;    // sum; k_action divides by 243
}

// ---------------- angle MLP: wave-autonomous, zero LDS, zero barriers ----------------
// Flat rows R = NF*17 = 264384. Wave: 3 tiles of 16 consecutive rows. grid = 1377.
__global__ __launch_bounds__(256) void k_angle(const float* __restrict__ src,
    const unsigned short* __restrict__ ws_wa,
    const float* __restrict__ ab1, const float* __restrict__ aw2,
    const float* __restrict__ ab2, float* __restrict__ out_pa)
{
  const int tid = threadIdx.x, w = tid >> 6, lane = tid & 63;
  const int g = lane >> 4, c = lane & 15;

  bf16x8 wa[4][4];
  #pragma unroll
  for (int kt = 0; kt < 4; ++kt)
    #pragma unroll
    for (int nf = 0; nf < 4; ++nf)
      wa[kt][nf] = __builtin_bit_cast(bf16x8, *(const u16x8*)&ws_wa[((kt*4 + nf)*64 + lane)*8]);

  float ab1c[4], aw2c[4][3];
  #pragma unroll
  for (int nf = 0; nf < 4; ++nf){
    const int col = nf*16 + c;
    ab1c[nf] = ab1[col];
    #pragma unroll
    for (int m = 0; m < 3; ++m) aw2c[nf][m] = aw2[col*3 + m];
  }
  const float ab2c[3] = {ab2[0], ab2[1], ab2[2]};

  const long rbase = (long)blockIdx.x*192 + w*48;
  #pragma unroll
  for (int i = 0; i < 3; ++i){
    const long r0 = rbase + i*16;
    f32x4 acc[4];
    #pragma unroll
    for (int nf = 0; nf < 4; ++nf) acc[nf] = (f32x4)0.0f;

    // issue all 8 loads for this tile up front
    float4 a0[4], a1[4];
    #pragma unroll
    for (int kt = 0; kt < 4; ++kt){
      const float* sp = src + (r0 + c)*NC + kt*32 + g*8;
      a0[kt] = *(const float4*)sp;
      a1[kt] = *(const float4*)(sp + 4);
    }
    #pragma unroll
    for (int kt = 0; kt < 4; ++kt){
      u16x8 t;
      t[0]=bfc(a0[kt].x); t[1]=bfc(a0[kt].y); t[2]=bfc(a0[kt].z); t[3]=bfc(a0[kt].w);
      t[4]=bfc(a1[kt].x); t[5]=bfc(a1[kt].y); t[6]=bfc(a1[kt].z); t[7]=bfc(a1[kt].w);
      const bf16x8 av = __builtin_bit_cast(bf16x8, t);
      #pragma unroll
      for (int nf = 0; nf < 4; ++nf)
        acc[nf] = __builtin_amdgcn_mfma_f32_16x16x32_bf16(av, wa[kt][nf], acc[nf], 0, 0, 0);
    }

    float s[4][3];
    #pragma unroll
    for (int r = 0; r < 4; ++r){ s[r][0]=0.f; s[r][1]=0.f; s[r][2]=0.f; }
    #pragma unroll
    for (int nf = 0; nf < 4; ++nf)
      #pragma unroll
      for (int r = 0; r < 4; ++r){
        const float h = gelu_fast(acc[nf][r] + ab1c[nf]);
        s[r][0] = fmaf(h, aw2c[nf][0], s[r][0]);
        s[r][1] = fmaf(h, aw2c[nf][1], s[r][1]);
        s[r][2] = fmaf(h, aw2c[nf][2], s[r][2]);
      }
    #pragma unroll
    for (int r = 0; r < 4; ++r)
      #pragma unroll
      for (int m = 0; m < 3; ++m){
        float v = s[r][m];
        v += __shfl_xor(v, 1);
        v += __shfl_xor(v, 2);
        v += __shfl_xor(v, 4);
        v += __shfl_xor(v, 8);
        s[r][m] = v;
      }
    if (c == 0){
      #pragma unroll
      for (int r = 0; r < 4; ++r){
        const long row = r0 + g*4 + r;
        #pragma unroll
        for (int m = 0; m < 3; ++m)
          out_pa[row*3 + m] = s[r][m] + ab2c[m];
      }
    }
  }
}

// ---------------- bone MLP: one wave = one frame, 2-deep load pipeline ----------------
__global__ __launch_bounds__(256) void k_bone(const float* __restrict__ src,
    const unsigned short* __restrict__ ws_wb,
    const float* __restrict__ bb1, const float* __restrict__ bw2,
    const float* __restrict__ bb2, float* __restrict__ out_pbl)
{
  const int tid = threadIdx.x, w = tid >> 6, lane = tid & 63;
  const int g = lane >> 4, c = lane & 15;

  float bb1c[8], bw2c[8];
  #pragma unroll
  for (int P = 0; P < 8; ++P){ bb1c[P] = bb1[P*16 + c]; bw2c[P] = bw2[P*16 + c]; }
  const float bb2c = bb2[0];
  const int jAo = d_cA16[c]*NC, jBo = d_cB16[c]*NC;

  auto loadA = [&](float4 (&r0)[8], float4 (&r1)[8], long frame){
    const float* fb = src + frame*JC;
    #pragma unroll
    for (int ks = 0; ks < 8; ++ks){
      const float* pa = fb + (ks < 4 ? jAo : jBo) + (ks & 3)*32 + g*8;
      r0[ks] = *(const float4*)pa;
      r1[ks] = *(const float4*)(pa + 4);
    }
  };
  auto cvtA = [&](bf16x8 (&af)[8], const float4 (&r0)[8], const float4 (&r1)[8]){
    #pragma unroll
    for (int ks = 0; ks < 8; ++ks){
      u16x8 t;
      t[0]=bfc(r0[ks].x); t[1]=bfc(r0[ks].y); t[2]=bfc(r0[ks].z); t[3]=bfc(r0[ks].w);
      t[4]=bfc(r1[ks].x); t[5]=bfc(r1[ks].y); t[6]=bfc(r1[ks].z); t[7]=bfc(r1[ks].w);
      af[ks] = __builtin_bit_cast(bf16x8, t);
    }
  };

  const long fbase = (long)blockIdx.x*12 + w*3;
  float4 c0[8], c1[8], n0[8], n1[8];
  loadA(c0, c1, fbase);

  #pragma unroll
  for (int i = 0; i < 3; ++i){
    const long frame = fbase + i;
    if (i < 2) loadA(n0, n1, frame + 1);   // in flight during compute

    bf16x8 af[8];
    cvtA(af, c0, c1);

    float s[4] = {0.f, 0.f, 0.f, 0.f};
    #pragma unroll
    for (int nfp = 0; nfp < 4; ++nfp){
      f32x4 acc0 = (f32x4)0.0f, acc1 = (f32x4)0.0f;
      #pragma unroll
      for (int ks = 0; ks < 8; ++ks){
        const bf16x8 wb0 = __builtin_bit_cast(bf16x8,
            *(const u16x8*)&ws_wb[(((nfp*2 + 0)*8 + ks)*64 + lane)*8]);
        const bf16x8 wb1 = __builtin_bit_cast(bf16x8,
            *(const u16x8*)&ws_wb[(((nfp*2 + 1)*8 + ks)*64 + lane)*8]);
        acc0 = __builtin_amdgcn_mfma_f32_16x16x32_bf16(af[ks], wb0, acc0, 0, 0, 0);
        acc1 = __builtin_amdgcn_mfma_f32_16x16x32_bf16(af[ks], wb1, acc1, 0, 0, 0);
      }
      #pragma unroll
      for (int r = 0; r < 4; ++r)
        s[r] += gelu_fast(acc0[r] + bb1c[nfp*2    ]) * bw2c[nfp*2    ]
              + gelu_fast(acc1[r] + bb1c[nfp*2 + 1]) * bw2c[nfp*2 + 1];
    }
    #pragma unroll
    for (int r = 0; r < 4; ++r){
      s[r] += __shfl_xor(s[r], 1);
      s[r] += __shfl_xor(s[r], 2);
      s[r] += __shfl_xor(s[r], 4);
      s[r] += __shfl_xor(s[r], 8);
    }
    if (c == 0){
      #pragma unroll
      for (int r = 0; r < 4; ++r){
        const int bone = g*4 + r;
        if (bone < 15)
          out_pbl[frame*15 + bone] = fmaxf(s[r] + bb2c, 0.0f);
      }
    }
    #pragma unroll
    for (int ks = 0; ks < 8; ++ks){ c0[ks] = n0[ks]; c1[ks] = n1[ks]; }
  }
}

// ---------------- action classifier (reads per-batch sums) ----------------
__global__ __launch_bounds__(256) void k_action(const float* __restrict__ sum_src,
    const float* __restrict__ cw1, const float* __restrict__ cb1,
    const float* __restrict__ cw2, const float* __restrict__ cb2,
    float* __restrict__ out_lg)
{
  __shared__ float s_m[JC];
  __shared__ float s_part[4][64];
  __shared__ float s_h[64];
  const int b = blockIdx.x, tid = threadIdx.x;
  for (int i = tid; i < JC; i += 256) s_m[i] = sum_src[(long)b*JC + i] * (1.0f/243.0f);
  __syncthreads();
  const int n = tid & 63, part = tid >> 6;
  float s = 0.0f;
  const int k0 = part * 544;
  for (int k = k0; k < k0 + 544; ++k) s = fmaf(s_m[k], cw1[(long)k*64 + n], s);
  s_part[part][n] = s;
  __syncthreads();
  if (tid < 64) s_h[tid] = gelu_exact(s_part[0][tid] + s_part[1][tid] +
                                      s_part[2][tid] + s_part[3][tid] + cb1[tid]);
  __syncthreads();
  if (tid < 8){
    float v = cb2[tid];
    #pragma unroll
    for (int k = 0; k < 64; ++k) v = fmaf(s_h[k], cw2[k*8 + tid], v);
    out_lg[b*8 + tid] = v;
  }
}

extern "C" void kernel_launch(void* const* d_in, const int* in_sizes, int n_in,
                              void* d_out, int out_size, void* d_ws, size_t ws_size,
                              hipStream_t stream)
{
  const float* feat = (const float*)d_in[0];
  const float* pose = (const float*)d_in[1];
  const float* aw1  = (const float*)d_in[2];
  const float* ab1  = (const float*)d_in[3];
  const float* aw2  = (const float*)d_in[4];
  const float* ab2  = (const float*)d_in[5];
  const float* bw1  = (const float*)d_in[6];
  const float* bb1  = (const float*)d_in[7];
  const float* bw2  = (const float*)d_in[8];
  const float* bb2  = (const float*)d_in[9];
  const float* cw1  = (const float*)d_in[10];
  const float* cb1  = (const float*)d_in[11];
  const float* cw2  = (const float*)d_in[12];
  const float* cb2  = (const float*)d_in[13];

  float* out = (float*)d_out;
  float* out_pa  = out;                 // [NF,17,3]  793152
  float* out_aa  = out + 793152;        // [NF,17,1]  264384
  float* out_pbl = out + 1057536;       // [NF,15,1]  233280
  float* out_abl = out + 1290816;       // [NF,15,1]  233280
  float* out_lg  = out + 1524096;       // [64,8]     512

  float* mean_acc = (float*)d_ws;
  unsigned short* ws_wb = (unsigned short*)((char*)d_ws + WSO_WB);
  unsigned short* ws_wa = (unsigned short*)((char*)d_ws + WSO_WA);

  k_prep<<<dim3(20), dim3(256), 0, stream>>>(bw1, aw1, ws_wb, ws_wa);
  k_geom<<<dim3((NF + 255)/256), dim3(256), 0, stream>>>(pose, out_aa, out_abl);
  k_mean<<<dim3((JC + 255)/256, 64), dim3(256), 0, stream>>>(feat, mean_acc);
  k_angle<<<dim3((NF*NJ)/192), dim3(256), 0, stream>>>(feat, ws_wa, ab1, aw2, ab2, out_pa);
  k_bone<<<dim3(NF/12), dim3(256), 0, stream>>>(feat, ws_wb, bb1, bw2, bb2, out_pbl);
  k_action<<<dim3(64), dim3(256), 0, stream>>>(mean_acc, cw1, cb1, cw2, cb2, out_lg);
}